// Round 21
// baseline (409.783 us; speedup 1.0000x reference)
//
#include <hip/hip_runtime.h>

#define NPTS   32768
#define DIM    256
#define KCODES 8192
#define TAU    1e-2f
#define TAU2   3e-2f
#define NCAP   16384

typedef __attribute__((ext_vector_type(8))) short bf16x8;
typedef __attribute__((ext_vector_type(4))) float f32x4;

__device__ __forceinline__ unsigned short f2bf(float x) {  // RNE bf16
  unsigned u = __float_as_uint(x);
  unsigned r = (u + 0x7fffu + ((u >> 16) & 1u)) >> 16;
  return (unsigned short)r;
}

// ---------------- bf16 quantize + row squared-norms ----------------
__global__ __launch_bounds__(256) void bf16_norms_kernel(
    const float* __restrict__ src, unsigned short* __restrict__ hi,
    float* __restrict__ norms, int* __restrict__ flagcnt) {
  if (flagcnt && blockIdx.x == 0 && threadIdx.x == 0) *flagcnt = 0;
  int row = blockIdx.x * 4 + (threadIdx.x >> 6);
  int lane = threadIdx.x & 63;
  float4 a = reinterpret_cast<const float4*>(src)[row * 64 + lane];
  ushort4 hq;
  hq.x = f2bf(a.x); hq.y = f2bf(a.y); hq.z = f2bf(a.z); hq.w = f2bf(a.w);
  reinterpret_cast<ushort4*>(hi)[row * 64 + lane] = hq;
  float sx = a.x * a.x, sy = a.y * a.y, sz = a.z * a.z, sw = a.w * a.w;
  double s = (double)sx + (double)sy + (double)sz + (double)sw;
#pragma unroll
  for (int m = 32; m; m >>= 1) s += __shfl_xor(s, m, 64);
  if (lane == 0) norms[row] = (float)s;
}

// standalone norms (fallback path)
__global__ __launch_bounds__(256) void norms_kernel(const float* __restrict__ src,
                                                    float* __restrict__ dst) {
  int row = blockIdx.x * 4 + (threadIdx.x >> 6);
  int lane = threadIdx.x & 63;
  float4 a = reinterpret_cast<const float4*>(src)[row * 64 + lane];
  float sx = a.x * a.x, sy = a.y * a.y, sz = a.z * a.z, sw = a.w * a.w;
  double s = (double)sx + (double)sy + (double)sz + (double)sw;
#pragma unroll
  for (int m = 32; m; m >>= 1) s += __shfl_xor(s, m, 64);
  if (lane == 0) dst[row] = (float)s;
}

// ---------------- 1-pass bf16 MFMA distance GEMM + per-point top-2 ----------
// (verbatim r20: swapped operands, sans-h2 scores, per-lane top-2, end merge)
__global__ __launch_bounds__(512, 2) void mfma_argmin_kernel(
    const unsigned short* __restrict__ hh, const unsigned short* __restrict__ chh,
    const float* __restrict__ c2f,
    float* __restrict__ bv, int* __restrict__ bi, float* __restrict__ b2o) {
  __shared__ __align__(16) unsigned short Ps[8192], Cs[8192];  // 16+16 KB
  __shared__ float tb1[128][4], tb2[128][4];                   // 4 KB
  __shared__ int ti1[128][4];                                  // 2 KB
  const int t = threadIdx.x;
  const int lane = t & 63;
  const int wid = t >> 6;
  const int wrow = wid >> 2;      // 0..1  point-half
  const int cgroup = wid & 3;     // 0..3  code-quarter
  const int b = blockIdx.x;
  const int v = (b & 7) * 64 + (b >> 3);   // XCD-chunked bijective swizzle
  const int sblk = v >> 8, pblk = v & 255;
  const int p0 = pblk * 128;
  const int cbase = sblk * (KCODES / 2);

  const int strow = t >> 2, stc = t & 3;
  const int ssw = strow & 7;
  const int stbase = strow * 128;
  const int wd0 = stbase + (((stc * 2) ^ ssw) << 4);
  const int wd1 = stbase + (((stc * 2 + 1) ^ ssw) << 4);
  const char* hhc = (const char*)hh;
  const char* chc = (const char*)chh;
  const unsigned poffs = (unsigned)(p0 + strow) * 512u + (unsigned)(stc * 32);
  const unsigned cbb = (unsigned)(cbase + strow) * 512u + (unsigned)(stc * 32);

  const int flane = lane & 15, fch = lane >> 4;
  int coff[2][2];
#pragma unroll
  for (int cr = 0; cr < 2; ++cr) {
    int ar = cgroup * 32 + cr * 16 + flane;
#pragma unroll
    for (int kp = 0; kp < 2; ++kp)
      coff[cr][kp] = ar * 128 + (((kp * 4 + fch) ^ (ar & 7)) << 4);
  }
  int poff[4][2];
#pragma unroll
  for (int pc = 0; pc < 4; ++pc) {
    int br = wrow * 64 + pc * 16 + flane;
#pragma unroll
    for (int kp = 0; kp < 2; ++kp)
      poff[pc][kp] = br * 128 + (((kp * 4 + fch) ^ (br & 7)) << 4);
  }

  float rb1[4], rb2[4];
  int ri1[4];
#pragma unroll
  for (int pc = 0; pc < 4; ++pc) { rb1[pc] = 3.4e38f; rb2[pc] = 3.4e38f; ri1[pc] = 0; }

#pragma unroll 1
  for (int cc = 0; cc < 32; ++cc) {
    f32x4 acc[8];
#pragma unroll
    for (int q = 0; q < 8; ++q) acc[q] = (f32x4){0.f, 0.f, 0.f, 0.f};
    const unsigned ccc = cbb + (unsigned)cc * 65536u;

#pragma unroll
    for (int dd = 0; dd < 4; ++dd) {
      const unsigned kk = (unsigned)(dd * 128);
      uint4 pa = *(const uint4*)(hhc + poffs + kk);
      uint4 pb = *(const uint4*)(hhc + poffs + kk + 16);
      uint4 ca = *(const uint4*)(chc + ccc + kk);
      uint4 cb2 = *(const uint4*)(chc + ccc + kk + 16);
      __syncthreads();
      *(uint4*)((char*)Ps + wd0) = pa;
      *(uint4*)((char*)Ps + wd1) = pb;
      *(uint4*)((char*)Cs + wd0) = ca;
      *(uint4*)((char*)Cs + wd1) = cb2;
      __syncthreads();
      bf16x8 cf[2][2];
#pragma unroll
      for (int cr = 0; cr < 2; ++cr)
#pragma unroll
        for (int kp = 0; kp < 2; ++kp)
          cf[cr][kp] = *(const bf16x8*)((const char*)Cs + coff[cr][kp]);
#pragma unroll
      for (int pc = 0; pc < 4; ++pc) {
        bf16x8 p0f = *(const bf16x8*)((const char*)Ps + poff[pc][0]);
        bf16x8 p1f = *(const bf16x8*)((const char*)Ps + poff[pc][1]);
        acc[pc] = __builtin_amdgcn_mfma_f32_16x16x32_bf16(cf[0][0], p0f, acc[pc], 0, 0, 0);
        acc[pc] = __builtin_amdgcn_mfma_f32_16x16x32_bf16(cf[0][1], p1f, acc[pc], 0, 0, 0);
        acc[4 + pc] = __builtin_amdgcn_mfma_f32_16x16x32_bf16(cf[1][0], p0f, acc[4 + pc], 0, 0, 0);
        acc[4 + pc] = __builtin_amdgcn_mfma_f32_16x16x32_bf16(cf[1][1], p1f, acc[4 + pc], 0, 0, 0);
      }
    }
    const int code0 = cbase + cc * 128 + cgroup * 32 + fch * 4;
    float c2v[2][4];
#pragma unroll
    for (int cr = 0; cr < 2; ++cr)
#pragma unroll
      for (int r = 0; r < 4; ++r)
        c2v[cr][r] = c2f[code0 + cr * 16 + r];
#pragma unroll
    for (int pc = 0; pc < 4; ++pc) {
#pragma unroll
      for (int cr = 0; cr < 2; ++cr)
#pragma unroll
        for (int r = 0; r < 4; ++r) {
          float sv = fmaf(-2.f, acc[cr * 4 + pc][r], c2v[cr][r]);
          if (sv < rb1[pc]) { rb2[pc] = rb1[pc]; rb1[pc] = sv; ri1[pc] = code0 + cr * 16 + r; }
          else if (sv < rb2[pc]) rb2[pc] = sv;
        }
    }
  }
#pragma unroll
  for (int pc = 0; pc < 4; ++pc) {
    float b1 = rb1[pc], b2 = rb2[pc];
    int i1 = ri1[pc];
#pragma unroll
    for (int m = 16; m <= 32; m <<= 1) {
      float ob1 = __shfl_xor(b1, m, 64);
      int oi1 = __shfl_xor(i1, m, 64);
      float ob2 = __shfl_xor(b2, m, 64);
      float loser = fmaxf(b1, ob1);
      float nb2 = fminf(fminf(b2, ob2), loser);
      if (ob1 < b1 || (ob1 == b1 && oi1 < i1)) { b1 = ob1; i1 = oi1; }
      b2 = nb2;
    }
    if (fch == 0) {
      int pl = wrow * 64 + pc * 16 + flane;
      tb1[pl][cgroup] = b1;
      ti1[pl][cgroup] = i1;
      tb2[pl][cgroup] = b2;
    }
  }
  __syncthreads();
  if (t < 128) {
    float b1 = tb1[t][0], b2 = tb2[t][0];
    int i1 = ti1[t][0];
#pragma unroll
    for (int w = 1; w < 4; ++w) {
      float nb1 = tb1[t][w], nb2v = tb2[t][w];
      int ni1 = ti1[t][w];
      float loser = fmaxf(b1, nb1);
      float m2 = fminf(fminf(b2, nb2v), loser);
      if (nb1 < b1 || (nb1 == b1 && ni1 < i1)) { b1 = nb1; i1 = ni1; }
      b2 = m2;
    }
    int p = p0 + t;
    bv[sblk * NPTS + p] = b1;
    bi[sblk * NPTS + p] = i1;
    b2o[sblk * NPTS + p] = b2;
  }
}

// ---------------- merge 2 slices + flag near-ties (+bminc, cnt init) --------
__global__ __launch_bounds__(256) void merge_flag_kernel(
    const float* __restrict__ bv, const int* __restrict__ bi,
    const float* __restrict__ b2o, int* __restrict__ idx,
    float* __restrict__ out_idx_f, int* __restrict__ flagcnt,
    int* __restrict__ flaglist, float* __restrict__ bminc,
    int* __restrict__ cnt) {
  int p = blockIdx.x * 256 + threadIdx.x;
  float b1 = bv[p]; int i1 = bi[p]; float b2 = b2o[p];
  {
    float pb1 = bv[NPTS + p];
    int pi1 = bi[NPTS + p];
    float pb2 = b2o[NPTS + p];
    float loser = fmaxf(b1, pb1);
    float nb2 = fminf(fminf(b2, pb2), loser);
    if (pb1 < b1 || (pb1 == b1 && pi1 < i1)) { b1 = pb1; i1 = pi1; }
    b2 = nb2;
  }
  idx[p] = i1;
  out_idx_f[p] = (float)i1;
  if (b2 - b1 < TAU) {
    int s = atomicAdd(flagcnt, 1);
    flaglist[s] = p;
    if (s < NCAP) { bminc[s] = b1; cnt[s] = 0; }
  }
}

// ---------------- candidate collection: re-run approx GEMM on flagged pts ---
// Clone of mfma_argmin with P-rows gathered via flaglist; epilogue appends
// codes with score < bminc[e] + TAU2 (the numpy winner is provably inside:
// approx(w) <= b1 + 2*eps, eps6sigma ~1.5e-2 < TAU2). Approx winner always
// self-appends (sv == b1) -> cnt >= 1. Append order irrelevant (min is
// (val,idx)-lexicographic downstream).
__global__ __launch_bounds__(512, 2) void collect_kernel(
    const unsigned short* __restrict__ hh, const unsigned short* __restrict__ chh,
    const float* __restrict__ c2f, const int* __restrict__ flagcnt,
    const int* __restrict__ flaglist, const float* __restrict__ bminc,
    int* __restrict__ cnt, int* __restrict__ cand) {
  __shared__ __align__(16) unsigned short Ps[8192], Cs[8192];
  const int n0 = *flagcnt;
  const int n = n0 > NCAP ? NCAP : n0;
  const int pblk = blockIdx.x >> 1;
  const int sblk = blockIdx.x & 1;
  const int p0c = pblk * 128;
  if (p0c >= n) return;
  const int t = threadIdx.x;
  const int lane = t & 63;
  const int wid = t >> 6;
  const int wrow = wid >> 2;
  const int cgroup = wid & 3;
  const int cbase = sblk * (KCODES / 2);

  const int strow = t >> 2, stc = t & 3;
  const int ssw = strow & 7;
  const int stbase = strow * 128;
  const int wd0 = stbase + (((stc * 2) ^ ssw) << 4);
  const int wd1 = stbase + (((stc * 2 + 1) ^ ssw) << 4);
  const char* hhc = (const char*)hh;
  const char* chc = (const char*)chh;
  const int prow_e = p0c + strow;
  const int prow = (prow_e < n) ? flaglist[prow_e] : flaglist[0];
  const unsigned poffs = (unsigned)prow * 512u + (unsigned)(stc * 32);
  const unsigned cbb = (unsigned)(cbase + strow) * 512u + (unsigned)(stc * 32);

  const int flane = lane & 15, fch = lane >> 4;
  int coff[2][2];
#pragma unroll
  for (int cr = 0; cr < 2; ++cr) {
    int ar = cgroup * 32 + cr * 16 + flane;
#pragma unroll
    for (int kp = 0; kp < 2; ++kp)
      coff[cr][kp] = ar * 128 + (((kp * 4 + fch) ^ (ar & 7)) << 4);
  }
  int poff[4][2];
#pragma unroll
  for (int pc = 0; pc < 4; ++pc) {
    int br = wrow * 64 + pc * 16 + flane;
#pragma unroll
    for (int kp = 0; kp < 2; ++kp)
      poff[pc][kp] = br * 128 + (((kp * 4 + fch) ^ (br & 7)) << 4);
  }

  int ept[4];
  float thr[4];
#pragma unroll
  for (int pc = 0; pc < 4; ++pc) {
    int e = p0c + wrow * 64 + pc * 16 + flane;
    ept[pc] = e;
    thr[pc] = (e < n) ? (bminc[e] + TAU2) : -3.4e38f;
  }

#pragma unroll 1
  for (int cc = 0; cc < 32; ++cc) {
    f32x4 acc[8];
#pragma unroll
    for (int q = 0; q < 8; ++q) acc[q] = (f32x4){0.f, 0.f, 0.f, 0.f};
    const unsigned ccc = cbb + (unsigned)cc * 65536u;

#pragma unroll
    for (int dd = 0; dd < 4; ++dd) {
      const unsigned kk = (unsigned)(dd * 128);
      uint4 pa = *(const uint4*)(hhc + poffs + kk);
      uint4 pb = *(const uint4*)(hhc + poffs + kk + 16);
      uint4 ca = *(const uint4*)(chc + ccc + kk);
      uint4 cb2 = *(const uint4*)(chc + ccc + kk + 16);
      __syncthreads();
      *(uint4*)((char*)Ps + wd0) = pa;
      *(uint4*)((char*)Ps + wd1) = pb;
      *(uint4*)((char*)Cs + wd0) = ca;
      *(uint4*)((char*)Cs + wd1) = cb2;
      __syncthreads();
      bf16x8 cf[2][2];
#pragma unroll
      for (int cr = 0; cr < 2; ++cr)
#pragma unroll
        for (int kp = 0; kp < 2; ++kp)
          cf[cr][kp] = *(const bf16x8*)((const char*)Cs + coff[cr][kp]);
#pragma unroll
      for (int pc = 0; pc < 4; ++pc) {
        bf16x8 p0f = *(const bf16x8*)((const char*)Ps + poff[pc][0]);
        bf16x8 p1f = *(const bf16x8*)((const char*)Ps + poff[pc][1]);
        acc[pc] = __builtin_amdgcn_mfma_f32_16x16x32_bf16(cf[0][0], p0f, acc[pc], 0, 0, 0);
        acc[pc] = __builtin_amdgcn_mfma_f32_16x16x32_bf16(cf[0][1], p1f, acc[pc], 0, 0, 0);
        acc[4 + pc] = __builtin_amdgcn_mfma_f32_16x16x32_bf16(cf[1][0], p0f, acc[4 + pc], 0, 0, 0);
        acc[4 + pc] = __builtin_amdgcn_mfma_f32_16x16x32_bf16(cf[1][1], p1f, acc[4 + pc], 0, 0, 0);
      }
    }
    const int code0 = cbase + cc * 128 + cgroup * 32 + fch * 4;
    float c2v[2][4];
#pragma unroll
    for (int cr = 0; cr < 2; ++cr)
#pragma unroll
      for (int r = 0; r < 4; ++r)
        c2v[cr][r] = c2f[code0 + cr * 16 + r];
#pragma unroll
    for (int pc = 0; pc < 4; ++pc) {
#pragma unroll
      for (int cr = 0; cr < 2; ++cr)
#pragma unroll
        for (int r = 0; r < 4; ++r) {
          float sv = fmaf(-2.f, acc[cr * 4 + pc][r], c2v[cr][r]);
          if (sv < thr[pc]) {
            int slot = atomicAdd(&cnt[ept[pc]], 1);
            if (slot < 32) cand[ept[pc] * 32 + slot] = code0 + cr * 16 + r;
          }
        }
    }
  }
}

// ---------------- exact numpy-semantics rescoring of candidates --------------
// 8 points/block, 32 threads/point (one per candidate slot). Exact score =
// fl32(fl32(h2+c2) - 2*dot), dot = ascending-k sequential fma chain (the
// proven refine arithmetic). Lexicographic (val,idx) min over candidates.
__global__ __launch_bounds__(256) void cand_exact_kernel(
    const float* __restrict__ h, const float* __restrict__ cb,
    const float* __restrict__ h2f, const float* __restrict__ c2f,
    const int* __restrict__ flagcnt, const int* __restrict__ flaglist,
    const int* __restrict__ cnt, const int* __restrict__ cand,
    int* __restrict__ idx, float* __restrict__ out_idx_f) {
  __shared__ float hrows[8][DIM];  // 8 KB
  const int n0 = *flagcnt;
  const int n = n0 > NCAP ? NCAP : n0;
  const int e0 = blockIdx.x * 8;
  if (e0 >= n) return;
  for (int i = threadIdx.x; i < 8 * 64; i += 256) {
    int rr = i >> 6;
    int e = e0 + rr;
    if (e < n) {
      int p = flaglist[e];
      reinterpret_cast<float4*>(hrows[rr])[i & 63] =
          reinterpret_cast<const float4*>(h + (size_t)p * DIM)[i & 63];
    }
  }
  __syncthreads();
  const int rr = threadIdx.x >> 5;
  const int slot = threadIdx.x & 31;
  const int e = e0 + rr;
  float best = 3.4e38f;
  int besti = 0x7fffffff;
  bool valid = (e < n) && (cnt[e] <= 32);
  if (valid && slot < cnt[e]) {
    int c = cand[e * 32 + slot];
    const float4* crow = reinterpret_cast<const float4*>(cb + (size_t)c * DIM);
    const float* hr = hrows[rr];
    float dot = 0.f;
#pragma unroll 16
    for (int q = 0; q < DIM / 4; ++q) {
      float4 cv = crow[q];
      dot = fmaf(hr[4 * q + 0], cv.x, dot);
      dot = fmaf(hr[4 * q + 1], cv.y, dot);
      dot = fmaf(hr[4 * q + 2], cv.z, dot);
      dot = fmaf(hr[4 * q + 3], cv.w, dot);
    }
    float A = h2f[flaglist[e]] + c2f[c];
    best = fmaf(-2.f, dot, A);
    besti = c;
  }
#pragma unroll
  for (int m = 1; m <= 16; m <<= 1) {
    float ob = __shfl_xor(best, m, 32);
    int oi = __shfl_xor(besti, m, 32);
    if (ob < best || (ob == best && oi < besti)) { best = ob; besti = oi; }
  }
  if (valid && slot == 0) {
    int p = flaglist[e];
    idx[p] = besti;
    out_idx_f[p] = (float)besti;
  }
}

// ---------------- fallback full exact scan: overflow / e>=NCAP points -------
__global__ __launch_bounds__(256) void refine_left_kernel(
    const float* __restrict__ h, const float* __restrict__ cb,
    const float* __restrict__ h2f, const float* __restrict__ c2f,
    const int* __restrict__ flagcnt, const int* __restrict__ flaglist,
    const int* __restrict__ cnt,
    int* __restrict__ idx, float* __restrict__ out_idx_f) {
  __shared__ float hrow[DIM];
  __shared__ float rb[256];
  __shared__ int ri[256];
  const int ntot = *flagcnt;
  for (int e = blockIdx.x; e < ntot; e += gridDim.x) {
    bool needs = (e >= NCAP) || (cnt[e] > 32);
    if (!needs) continue;   // e is block-uniform -> barrier-safe
    const int p = flaglist[e];
    __syncthreads();
    if (threadIdx.x < DIM / 4)
      reinterpret_cast<float4*>(hrow)[threadIdx.x] =
          reinterpret_cast<const float4*>(h + (size_t)p * DIM)[threadIdx.x];
    __syncthreads();
    const float h2 = h2f[p];
    float b1 = 3.4e38f;
    int i1 = 0x7fffffff;
    for (int c = threadIdx.x; c < KCODES; c += 256) {
      const float4* crow = reinterpret_cast<const float4*>(cb + (size_t)c * DIM);
      float dot = 0.f;
#pragma unroll 16
      for (int d4 = 0; d4 < DIM / 4; ++d4) {
        float4 cv = crow[d4];
        dot = fmaf(hrow[4 * d4 + 0], cv.x, dot);
        dot = fmaf(hrow[4 * d4 + 1], cv.y, dot);
        dot = fmaf(hrow[4 * d4 + 2], cv.z, dot);
        dot = fmaf(hrow[4 * d4 + 3], cv.w, dot);
      }
      float A = h2 + c2f[c];
      float s = fmaf(-2.f, dot, A);
      if (s < b1) { b1 = s; i1 = c; }
    }
    rb[threadIdx.x] = b1;
    ri[threadIdx.x] = i1;
    __syncthreads();
    for (int step = 128; step; step >>= 1) {
      if (threadIdx.x < step) {
        float ob = rb[threadIdx.x + step];
        int oi = ri[threadIdx.x + step];
        if (ob < rb[threadIdx.x] || (ob == rb[threadIdx.x] && oi < ri[threadIdx.x])) {
          rb[threadIdx.x] = ob;
          ri[threadIdx.x] = oi;
        }
      }
      __syncthreads();
    }
    if (threadIdx.x == 0) { idx[p] = ri[0]; out_idx_f[p] = (float)ri[0]; }
  }
}

// ---------------- fallback: r7 fp32 argmin (8x8 tile) + 2-way merge ----------
__global__ __launch_bounds__(512, 2) void argmin_fp32_kernel(
    const float* __restrict__ h, const float* __restrict__ cb,
    const float* __restrict__ h2f, const float* __restrict__ c2f,
    float* __restrict__ bestval, int* __restrict__ bestidx) {
  __shared__ float hs[16][132];
  __shared__ float cs[16][260];
  const int t = threadIdx.x;
  const int ct = t & 31;
  const int pt = t >> 5;
  const int b = blockIdx.x;
  const int v = (b & 7) * 64 + (b >> 3);
  const int sblk = v >> 8;
  const int pblk = v & 255;
  const int p0 = pblk * 128;
  const int cbase = sblk * (KCODES / 2);
  float best[8]; int besti[8]; float h2r[8];
#pragma unroll
  for (int i = 0; i < 8; ++i) {
    best[i] = 3.4e38f; besti[i] = 0;
    h2r[i] = h2f[p0 + pt * 4 + ((i >> 2) << 6) + (i & 3)];
  }
#pragma unroll 1
  for (int cc = 0; cc < (KCODES / 2) / 256; ++cc) {
    const int c0 = cbase + cc * 256;
    float dot[8][8];
#pragma unroll
    for (int i = 0; i < 8; ++i)
#pragma unroll
      for (int j = 0; j < 8; ++j) dot[i][j] = 0.f;
#pragma unroll 1
    for (int dd = 0; dd < DIM / 16; ++dd) {
      const int d0 = dd * 16;
      {
        int p = t >> 2, k4 = (t & 3) << 2;
        float4 w = *reinterpret_cast<const float4*>(h + (p0 + p) * DIM + d0 + k4);
        hs[k4 + 0][p] = w.x; hs[k4 + 1][p] = w.y;
        hs[k4 + 2][p] = w.z; hs[k4 + 3][p] = w.w;
      }
#pragma unroll
      for (int l = 0; l < 2; ++l) {
        int F = t + l * 512;
        int c = F >> 2, k4 = (F & 3) << 2;
        float4 w = *reinterpret_cast<const float4*>(cb + (c0 + c) * DIM + d0 + k4);
        cs[k4 + 0][c] = w.x; cs[k4 + 1][c] = w.y;
        cs[k4 + 2][c] = w.z; cs[k4 + 3][c] = w.w;
      }
      __syncthreads();
#pragma unroll
      for (int k = 0; k < 16; ++k) {
        float hv[8], cv[8];
        *reinterpret_cast<float4*>(&hv[0]) = *reinterpret_cast<const float4*>(&hs[k][pt * 4]);
        *reinterpret_cast<float4*>(&hv[4]) = *reinterpret_cast<const float4*>(&hs[k][pt * 4 + 64]);
        *reinterpret_cast<float4*>(&cv[0]) = *reinterpret_cast<const float4*>(&cs[k][ct * 4]);
        *reinterpret_cast<float4*>(&cv[4]) = *reinterpret_cast<const float4*>(&cs[k][ct * 4 + 128]);
#pragma unroll
        for (int i = 0; i < 8; ++i)
#pragma unroll
          for (int j = 0; j < 8; ++j) dot[i][j] = fmaf(hv[i], cv[j], dot[i][j]);
      }
      __syncthreads();
    }
#pragma unroll
    for (int j = 0; j < 8; ++j) {
      int cl = c0 + (ct << 2) + ((j >> 2) << 7) + (j & 3);
      float cc2 = c2f[cl];
#pragma unroll
      for (int i = 0; i < 8; ++i) {
        float A = h2r[i] + cc2;
        float s = A - 2.0f * dot[i][j];
        if (s < best[i]) { best[i] = s; besti[i] = cl; }
      }
    }
  }
#pragma unroll
  for (int i = 0; i < 8; ++i) {
    float b1 = best[i]; int i1 = besti[i];
#pragma unroll
    for (int m = 16; m; m >>= 1) {
      float so = __shfl_xor(b1, m, 64);
      int io = __shfl_xor(i1, m, 64);
      if (so < b1 || (so == b1 && io < i1)) { b1 = so; i1 = io; }
    }
    if (ct == 0) {
      int p = p0 + pt * 4 + ((i >> 2) << 6) + (i & 3);
      bestval[sblk * NPTS + p] = b1;
      bestidx[sblk * NPTS + p] = i1;
    }
  }
}

__global__ __launch_bounds__(256) void merge2_kernel(
    const float* __restrict__ bestval, const int* __restrict__ bestidx,
    int* __restrict__ idx, float* __restrict__ out_idx_f) {
  int p = blockIdx.x * 256 + threadIdx.x;
  float v0 = bestval[p], v1 = bestval[NPTS + p];
  int i0 = bestidx[p], i1 = bestidx[NPTS + p];
  int w = (v1 < v0) ? i1 : i0;
  idx[p] = w;
  out_idx_f[p] = (float)w;
}

// ---------------- gather + finalize ----------------
__global__ __launch_bounds__(256) void gather_kernel(
    const float* __restrict__ h, const float* __restrict__ cb,
    const unsigned char* __restrict__ maskb, const int* __restrict__ idx,
    float* __restrict__ zq, float* __restrict__ partial) {
  int p = blockIdx.x * 4 + (threadIdx.x >> 6);
  int lane = threadIdx.x & 63;
  int ci = idx[p];
  float4 hv = reinterpret_cast<const float4*>(h)[p * (DIM / 4) + lane];
  float4 zv = reinterpret_cast<const float4*>(cb)[ci * (DIM / 4) + lane];
  float4 q;
  q.x = hv.x + (zv.x - hv.x);
  q.y = hv.y + (zv.y - hv.y);
  q.z = hv.z + (zv.z - hv.z);
  q.w = hv.w + (zv.w - hv.w);
  reinterpret_cast<float4*>(zq)[p * (DIM / 4) + lane] = q;
  float dx = hv.x - zv.x, dy = hv.y - zv.y, dz = hv.z - zv.z, dw = hv.w - zv.w;
  float s = (maskb[p] != 0) ? (dx * dx + dy * dy + dz * dz + dw * dw) : 0.f;
#pragma unroll
  for (int m = 32; m; m >>= 1) s += __shfl_xor(s, m, 64);
  __shared__ float bs[4];
  if (lane == 0) bs[threadIdx.x >> 6] = s;
  __syncthreads();
  if (threadIdx.x == 0) partial[blockIdx.x] = bs[0] + bs[1] + bs[2] + bs[3];
}

__global__ __launch_bounds__(256) void finalize_kernel(
    const float* __restrict__ partial, const unsigned char* __restrict__ maskb,
    float* __restrict__ out_losses) {
  __shared__ float red[256];
  __shared__ int redi[256];
  float s = 0.f;
  for (int i = threadIdx.x; i < NPTS / 4; i += 256) s += partial[i];
  int cnt = 0;
  for (int i = threadIdx.x; i < NPTS; i += 256) cnt += (maskb[i] != 0);
  red[threadIdx.x] = s;
  redi[threadIdx.x] = cnt;
  __syncthreads();
  for (int step = 128; step; step >>= 1) {
    if (threadIdx.x < step) {
      red[threadIdx.x] += red[threadIdx.x + step];
      redi[threadIdx.x] += redi[threadIdx.x + step];
    }
    __syncthreads();
  }
  if (threadIdx.x == 0) {
    float denom = (float)redi[0] * (float)DIM + 1e-8f;
    float loss = red[0] / denom;
    out_losses[0] = loss;
    out_losses[1] = loss;
  }
}

extern "C" void kernel_launch(void* const* d_in, const int* in_sizes, int n_in,
                              void* d_out, int out_size, void* d_ws, size_t ws_size,
                              hipStream_t stream) {
  const float* h = (const float*)d_in[0];
  const unsigned char* maskb = (const unsigned char*)d_in[1];
  const float* cb = (const float*)d_in[2];

  float* out = (float*)d_out;
  float* zq = out;
  float* out_idx_f = out + NPTS * DIM;
  float* out_losses = out + NPTS * DIM + NPTS;

  char* ws = (char*)d_ws;
  const size_t REQ = 25165824ULL;  // 24 MB

  if (ws_size >= REQ) {
    float* h2f = (float*)(ws + 0);                    // 128K
    float* c2f = (float*)(ws + 131072);               // 32K
    float* bv = (float*)(ws + 163840);                // 256K (2 slices)
    int* bi = (int*)(ws + 425984);                    // 256K
    float* b2o = (float*)(ws + 688128);               // 256K
    float* bminc = (float*)(ws + 950272);             // 64K
    int* idx = (int*)(ws + 1015808);                  // 128K
    float* partial = (float*)(ws + 1146880);          // 32K
    int* flagcnt = (int*)(ws + 1179648);              // 4 (+pad)
    int* flaglist = (int*)(ws + 1183744);             // 128K
    int* cnt = (int*)(ws + 1314816);                  // 64K
    int* cand = (int*)(ws + 1380352);                 // 2M
    unsigned short* hh = (unsigned short*)(ws + 4194304);    // 16M
    unsigned short* chh = (unsigned short*)(ws + 20971520);  // 4M

    hipLaunchKernelGGL(bf16_norms_kernel, dim3(NPTS / 4), dim3(256), 0, stream,
                       h, hh, h2f, flagcnt);
    hipLaunchKernelGGL(bf16_norms_kernel, dim3(KCODES / 4), dim3(256), 0, stream,
                       cb, chh, c2f, (int*)nullptr);
    hipLaunchKernelGGL(mfma_argmin_kernel, dim3(512), dim3(512), 0, stream,
                       hh, chh, c2f, bv, bi, b2o);
    hipLaunchKernelGGL(merge_flag_kernel, dim3(NPTS / 256), dim3(256), 0, stream,
                       bv, bi, b2o, idx, out_idx_f, flagcnt, flaglist, bminc, cnt);
    hipLaunchKernelGGL(collect_kernel, dim3((NCAP / 128) * 2), dim3(512), 0, stream,
                       hh, chh, c2f, flagcnt, flaglist, bminc, cnt, cand);
    hipLaunchKernelGGL(cand_exact_kernel, dim3(NCAP / 8), dim3(256), 0, stream,
                       h, cb, h2f, c2f, flagcnt, flaglist, cnt, cand, idx, out_idx_f);
    hipLaunchKernelGGL(refine_left_kernel, dim3(2048), dim3(256), 0, stream,
                       h, cb, h2f, c2f, flagcnt, flaglist, cnt, idx, out_idx_f);
    hipLaunchKernelGGL(gather_kernel, dim3(NPTS / 4), dim3(256), 0, stream,
                       h, cb, maskb, idx, zq, partial);
    hipLaunchKernelGGL(finalize_kernel, dim3(1), dim3(256), 0, stream,
                       partial, maskb, out_losses);
  } else {
    float* h2f = (float*)(ws + 0);
    float* c2f = (float*)(ws + (128 << 10));
    float* bestval = (float*)(ws + (160 << 10));
    int* bestidx = (int*)(ws + (416 << 10));
    int* idx = (int*)(ws + (672 << 10));
    float* partial = (float*)(ws + (800 << 10));

    hipLaunchKernelGGL(norms_kernel, dim3(NPTS / 4), dim3(256), 0, stream, h, h2f);
    hipLaunchKernelGGL(norms_kernel, dim3(KCODES / 4), dim3(256), 0, stream, cb, c2f);
    hipLaunchKernelGGL(argmin_fp32_kernel, dim3(512), dim3(512), 0, stream,
                       h, cb, h2f, c2f, bestval, bestidx);
    hipLaunchKernelGGL(merge2_kernel, dim3(NPTS / 256), dim3(256), 0, stream,
                       bestval, bestidx, idx, out_idx_f);
    hipLaunchKernelGGL(gather_kernel, dim3(NPTS / 4), dim3(256), 0, stream,
                       h, cb, maskb, idx, zq, partial);
    hipLaunchKernelGGL(finalize_kernel, dim3(1), dim3(256), 0, stream,
                       partial, maskb, out_losses);
  }
}

// Round 22
// 388.040 us; speedup vs baseline: 1.0560x; 1.0560x over previous
//
#include <hip/hip_runtime.h>

#define NPTS   32768
#define DIM    256
#define KCODES 8192
#define TAU    1e-2f
#define NCAP   16384

typedef __attribute__((ext_vector_type(8))) short bf16x8;
typedef __attribute__((ext_vector_type(4))) float f32x4;

__device__ __forceinline__ unsigned short f2bf(float x) {  // RNE bf16
  unsigned u = __float_as_uint(x);
  unsigned r = (u + 0x7fffu + ((u >> 16) & 1u)) >> 16;
  return (unsigned short)r;
}

// ---------------- bf16 quantize + row squared-norms ----------------
__global__ __launch_bounds__(256) void bf16_norms_kernel(
    const float* __restrict__ src, unsigned short* __restrict__ hi,
    float* __restrict__ norms, int* __restrict__ flagcnt) {
  if (flagcnt && blockIdx.x == 0 && threadIdx.x == 0) *flagcnt = 0;
  int row = blockIdx.x * 4 + (threadIdx.x >> 6);
  int lane = threadIdx.x & 63;
  float4 a = reinterpret_cast<const float4*>(src)[row * 64 + lane];
  ushort4 hq;
  hq.x = f2bf(a.x); hq.y = f2bf(a.y); hq.z = f2bf(a.z); hq.w = f2bf(a.w);
  reinterpret_cast<ushort4*>(hi)[row * 64 + lane] = hq;
  float sx = a.x * a.x, sy = a.y * a.y, sz = a.z * a.z, sw = a.w * a.w;
  double s = (double)sx + (double)sy + (double)sz + (double)sw;
#pragma unroll
  for (int m = 32; m; m >>= 1) s += __shfl_xor(s, m, 64);
  if (lane == 0) norms[row] = (float)s;
}

// standalone norms (fallback path)
__global__ __launch_bounds__(256) void norms_kernel(const float* __restrict__ src,
                                                    float* __restrict__ dst) {
  int row = blockIdx.x * 4 + (threadIdx.x >> 6);
  int lane = threadIdx.x & 63;
  float4 a = reinterpret_cast<const float4*>(src)[row * 64 + lane];
  float sx = a.x * a.x, sy = a.y * a.y, sz = a.z * a.z, sw = a.w * a.w;
  double s = (double)sx + (double)sy + (double)sz + (double)sw;
#pragma unroll
  for (int m = 32; m; m >>= 1) s += __shfl_xor(s, m, 64);
  if (lane == 0) dst[row] = (float)s;
}

// ---------------- 1-pass bf16 MFMA distance GEMM + per-point top-2 ----------
// SWAPPED operands (A=codes, B=points -> D[code][point]): each lane holds
// 8 codes x 4 points, so per-point top-2 is top2-of-8 in-reg and the
// cross-lane merge is only over the 4 fch-lanes (2 shuffle steps). Running
// top-2 in LDS (wave-exclusive [pt][cgroup] RMW by fch==0 lanes). This is
// the session-best configuration (r19: argmin 241us, VGPR 56, Occ 42%).
__global__ __launch_bounds__(512, 2) void mfma_argmin_kernel(
    const unsigned short* __restrict__ hh, const unsigned short* __restrict__ chh,
    const float* __restrict__ h2f, const float* __restrict__ c2f,
    float* __restrict__ bv, int* __restrict__ bi, float* __restrict__ b2o) {
  __shared__ __align__(16) unsigned short Ps[8192], Cs[8192];  // 16+16 KB
  __shared__ float tb1[128][4], tb2[128][4];                   // 4 KB
  __shared__ int ti1[128][4];                                  // 2 KB
  const int t = threadIdx.x;
  const int lane = t & 63;
  const int wid = t >> 6;
  const int wrow = wid >> 2;      // 0..1  point-half
  const int cgroup = wid & 3;     // 0..3  code-quarter
  const int b = blockIdx.x;
  const int v = (b & 7) * 64 + (b >> 3);   // XCD-chunked bijective swizzle
  const int sblk = v >> 8, pblk = v & 255;
  const int p0 = pblk * 128;
  const int cbase = sblk * (KCODES / 2);

  // staging: thread t owns 32B (logical chunks 2c,2c+1) of row t>>2
  const int strow = t >> 2, stc = t & 3;
  const int ssw = strow & 7;
  const int stbase = strow * 128;
  const int wd0 = stbase + (((stc * 2) ^ ssw) << 4);
  const int wd1 = stbase + (((stc * 2 + 1) ^ ssw) << 4);
  const char* hhc = (const char*)hh;
  const char* chc = (const char*)chh;
  const unsigned poffs = (unsigned)(p0 + strow) * 512u + (unsigned)(stc * 32);
  const unsigned cbb = (unsigned)(cbase + strow) * 512u + (unsigned)(stc * 32);

  // fragment read offsets
  const int flane = lane & 15, fch = lane >> 4;
  int coff[2][2];   // A-operand: codes, rows cgroup*32 + cr*16 + flane
#pragma unroll
  for (int cr = 0; cr < 2; ++cr) {
    int ar = cgroup * 32 + cr * 16 + flane;
#pragma unroll
    for (int kp = 0; kp < 2; ++kp)
      coff[cr][kp] = ar * 128 + (((kp * 4 + fch) ^ (ar & 7)) << 4);
  }
  int poff[4][2];   // B-operand: points, rows wrow*64 + pc*16 + flane
#pragma unroll
  for (int pc = 0; pc < 4; ++pc) {
    int br = wrow * 64 + pc * 16 + flane;
#pragma unroll
    for (int kp = 0; kp < 2; ++kp)
      poff[pc][kp] = br * 128 + (((kp * 4 + fch) ^ (br & 7)) << 4);
  }

  // per-lane resident h2 for its 4 points
  float h2p[4];
#pragma unroll
  for (int pc = 0; pc < 4; ++pc)
    h2p[pc] = h2f[p0 + wrow * 64 + pc * 16 + flane];

  // init LDS top-2 state
  tb1[t >> 2][t & 3] = 3.4e38f;
  tb2[t >> 2][t & 3] = 3.4e38f;
  ti1[t >> 2][t & 3] = 0;

#pragma unroll 1
  for (int cc = 0; cc < 32; ++cc) {
    f32x4 acc[8];   // acc[cr*4+pc]
#pragma unroll
    for (int q = 0; q < 8; ++q) acc[q] = (f32x4){0.f, 0.f, 0.f, 0.f};
    const unsigned ccc = cbb + (unsigned)cc * 65536u;  // cc*128 rows * 512 B

#pragma unroll
    for (int dd = 0; dd < 4; ++dd) {
      const unsigned kk = (unsigned)(dd * 128);
      uint4 pa = *(const uint4*)(hhc + poffs + kk);
      uint4 pb = *(const uint4*)(hhc + poffs + kk + 16);
      uint4 ca = *(const uint4*)(chc + ccc + kk);
      uint4 cb2 = *(const uint4*)(chc + ccc + kk + 16);
      __syncthreads();  // previous stage fully consumed
      *(uint4*)((char*)Ps + wd0) = pa;
      *(uint4*)((char*)Ps + wd1) = pb;
      *(uint4*)((char*)Cs + wd0) = ca;
      *(uint4*)((char*)Cs + wd1) = cb2;
      __syncthreads();  // deposits visible
      bf16x8 cf[2][2];
#pragma unroll
      for (int cr = 0; cr < 2; ++cr)
#pragma unroll
        for (int kp = 0; kp < 2; ++kp)
          cf[cr][kp] = *(const bf16x8*)((const char*)Cs + coff[cr][kp]);
#pragma unroll
      for (int pc = 0; pc < 4; ++pc) {
        bf16x8 p0f = *(const bf16x8*)((const char*)Ps + poff[pc][0]);
        bf16x8 p1f = *(const bf16x8*)((const char*)Ps + poff[pc][1]);
        acc[pc] = __builtin_amdgcn_mfma_f32_16x16x32_bf16(cf[0][0], p0f, acc[pc], 0, 0, 0);
        acc[pc] = __builtin_amdgcn_mfma_f32_16x16x32_bf16(cf[0][1], p1f, acc[pc], 0, 0, 0);
        acc[4 + pc] = __builtin_amdgcn_mfma_f32_16x16x32_bf16(cf[1][0], p0f, acc[4 + pc], 0, 0, 0);
        acc[4 + pc] = __builtin_amdgcn_mfma_f32_16x16x32_bf16(cf[1][1], p1f, acc[4 + pc], 0, 0, 0);
      }
    }
    // epilogue: per lane, 8 codes (cr,r) x 4 points (pc)
    const int code0 = cbase + cc * 128 + cgroup * 32 + fch * 4;
    float c2v[2][4];
#pragma unroll
    for (int cr = 0; cr < 2; ++cr)
#pragma unroll
      for (int r = 0; r < 4; ++r)
        c2v[cr][r] = c2f[code0 + cr * 16 + r];
#pragma unroll
    for (int pc = 0; pc < 4; ++pc) {
      float b1 = 3.4e38f, b2 = 3.4e38f;
      int i1 = 0;
#pragma unroll
      for (int cr = 0; cr < 2; ++cr)
#pragma unroll
        for (int r = 0; r < 4; ++r) {
          float A = h2p[pc] + c2v[cr][r];
          float sv = fmaf(-2.f, acc[cr * 4 + pc][r], A);
          if (sv < b1) { b2 = b1; b1 = sv; i1 = code0 + cr * 16 + r; }
          else if (sv < b2) b2 = sv;
        }
      // cross-lane merge over the 4 fch-lanes (xor 16, 32)
#pragma unroll
      for (int m = 16; m <= 32; m <<= 1) {
        float ob1 = __shfl_xor(b1, m, 64);
        int oi1 = __shfl_xor(i1, m, 64);
        float ob2 = __shfl_xor(b2, m, 64);
        float loser = fmaxf(b1, ob1);
        float nb2 = fminf(fminf(b2, ob2), loser);
        if (ob1 < b1 || (ob1 == b1 && oi1 < i1)) { b1 = ob1; i1 = oi1; }
        b2 = nb2;
      }
      if (fch == 0) {
        int pl = wrow * 64 + pc * 16 + flane;
        float gb1 = tb1[pl][cgroup], gb2 = tb2[pl][cgroup];
        int gi1 = ti1[pl][cgroup];
        float loser = fmaxf(gb1, b1);
        float nb2 = fminf(fminf(gb2, b2), loser);
        if (b1 < gb1 || (b1 == gb1 && i1 < gi1)) { gb1 = b1; gi1 = i1; }
        tb1[pl][cgroup] = gb1;
        ti1[pl][cgroup] = gi1;
        tb2[pl][cgroup] = nb2;
      }
    }
  }
  __syncthreads();
  // writeout: merge 4 cgroup entries per point (ascending, idx tiebreak)
  if (t < 128) {
    float b1 = tb1[t][0], b2 = tb2[t][0];
    int i1 = ti1[t][0];
#pragma unroll
    for (int w = 1; w < 4; ++w) {
      float nb1 = tb1[t][w], nb2v = tb2[t][w];
      int ni1 = ti1[t][w];
      float loser = fmaxf(b1, nb1);
      float m2 = fminf(fminf(b2, nb2v), loser);
      if (nb1 < b1 || (nb1 == b1 && ni1 < i1)) { b1 = nb1; i1 = ni1; }
      b2 = m2;
    }
    int p = p0 + t;
    bv[sblk * NPTS + p] = b1;
    bi[sblk * NPTS + p] = i1;
    b2o[sblk * NPTS + p] = b2;
  }
}

// ---------------- merge 2 slices + flag near-ties ----------------
__global__ __launch_bounds__(256) void merge_flag_kernel(
    const float* __restrict__ bv, const int* __restrict__ bi,
    const float* __restrict__ b2o, int* __restrict__ idx,
    float* __restrict__ out_idx_f, int* __restrict__ flagcnt,
    int* __restrict__ flaglist) {
  int p = blockIdx.x * 256 + threadIdx.x;
  float b1 = bv[p]; int i1 = bi[p]; float b2 = b2o[p];
  {
    float pb1 = bv[NPTS + p];
    int pi1 = bi[NPTS + p];
    float pb2 = b2o[NPTS + p];
    float loser = fmaxf(b1, pb1);
    float nb2 = fminf(fminf(b2, pb2), loser);
    if (pb1 < b1 || (pb1 == b1 && pi1 < i1)) { b1 = pb1; i1 = pi1; }
    b2 = nb2;
  }
  idx[p] = i1;
  out_idx_f[p] = (float)i1;
  if (b2 - b1 < TAU) { int s = atomicAdd(flagcnt, 1); flaglist[s] = p; }
}

// ---------------- compact flagged h-rows into contiguous buffer -------------
__global__ __launch_bounds__(256) void compact_kernel(
    const float* __restrict__ h, const float* __restrict__ h2f,
    const int* __restrict__ flagcnt, const int* __restrict__ flaglist,
    float* __restrict__ hc, float* __restrict__ h2c) {
  int n0 = *flagcnt;
  int n = n0 > NCAP ? NCAP : n0;
  int npad = (n + 127) & ~127;
  for (int e = blockIdx.x; e < npad; e += gridDim.x) {
    if (e < n) {
      int p = flaglist[e];
      if (threadIdx.x < 64)
        reinterpret_cast<float4*>(hc + (size_t)e * DIM)[threadIdx.x] =
            reinterpret_cast<const float4*>(h + (size_t)p * DIM)[threadIdx.x];
      if (threadIdx.x == 0) h2c[e] = h2f[p];
    } else {
      if (threadIdx.x < 64)
        reinterpret_cast<float4*>(hc + (size_t)e * DIM)[threadIdx.x] =
            make_float4(0.f, 0.f, 0.f, 0.f);
      if (threadIdx.x == 0) h2c[e] = 0.f;
    }
  }
}

// ---------------- exact fp32 GEMM re-argmin over compacted points -----------
__global__ __launch_bounds__(512, 2) void refine_gemm_kernel(
    const float* __restrict__ hc, const float* __restrict__ cb,
    const float* __restrict__ h2c, const float* __restrict__ c2f,
    const int* __restrict__ flagcnt,
    float* __restrict__ bv16, int* __restrict__ bi16) {
  const int n0 = *flagcnt;
  const int n = n0 > NCAP ? NCAP : n0;
  const int slice = blockIdx.x & 15;
  const int pblk = blockIdx.x >> 4;
  if (pblk * 128 >= n) return;
  __shared__ float hs[16][132];
  __shared__ float cs[16][260];
  const int t = threadIdx.x;
  const int ct = t & 31;
  const int pt = t >> 5;
  const int p0 = pblk * 128;
  const int cbase = slice * 512;
  float best[8]; int besti[8]; float h2r[8];
#pragma unroll
  for (int i = 0; i < 8; ++i) {
    best[i] = 3.4e38f; besti[i] = 0;
    h2r[i] = h2c[p0 + pt * 4 + ((i >> 2) << 6) + (i & 3)];
  }
#pragma unroll 1
  for (int cc = 0; cc < 2; ++cc) {
    const int c0 = cbase + cc * 256;
    float dot[8][8];
#pragma unroll
    for (int i = 0; i < 8; ++i)
#pragma unroll
      for (int j = 0; j < 8; ++j) dot[i][j] = 0.f;
#pragma unroll 1
    for (int dd = 0; dd < DIM / 16; ++dd) {
      const int d0 = dd * 16;
      {
        int p = t >> 2, k4 = (t & 3) << 2;
        float4 w = *reinterpret_cast<const float4*>(hc + (size_t)(p0 + p) * DIM + d0 + k4);
        hs[k4 + 0][p] = w.x; hs[k4 + 1][p] = w.y;
        hs[k4 + 2][p] = w.z; hs[k4 + 3][p] = w.w;
      }
#pragma unroll
      for (int l = 0; l < 2; ++l) {
        int F = t + l * 512;
        int c = F >> 2, k4 = (F & 3) << 2;
        float4 w = *reinterpret_cast<const float4*>(cb + (size_t)(c0 + c) * DIM + d0 + k4);
        cs[k4 + 0][c] = w.x; cs[k4 + 1][c] = w.y;
        cs[k4 + 2][c] = w.z; cs[k4 + 3][c] = w.w;
      }
      __syncthreads();
#pragma unroll
      for (int k = 0; k < 16; ++k) {
        float hv[8], cv[8];
        *reinterpret_cast<float4*>(&hv[0]) = *reinterpret_cast<const float4*>(&hs[k][pt * 4]);
        *reinterpret_cast<float4*>(&hv[4]) = *reinterpret_cast<const float4*>(&hs[k][pt * 4 + 64]);
        *reinterpret_cast<float4*>(&cv[0]) = *reinterpret_cast<const float4*>(&cs[k][ct * 4]);
        *reinterpret_cast<float4*>(&cv[4]) = *reinterpret_cast<const float4*>(&cs[k][ct * 4 + 128]);
#pragma unroll
        for (int i = 0; i < 8; ++i)
#pragma unroll
          for (int j = 0; j < 8; ++j) dot[i][j] = fmaf(hv[i], cv[j], dot[i][j]);
      }
      __syncthreads();
    }
#pragma unroll
    for (int j = 0; j < 8; ++j) {
      int cl = c0 + (ct << 2) + ((j >> 2) << 7) + (j & 3);
      float cc2 = c2f[cl];
#pragma unroll
      for (int i = 0; i < 8; ++i) {
        float A = h2r[i] + cc2;
        float s = A - 2.0f * dot[i][j];
        if (s < best[i]) { best[i] = s; besti[i] = cl; }
      }
    }
  }
#pragma unroll
  for (int i = 0; i < 8; ++i) {
    float b1 = best[i]; int i1 = besti[i];
#pragma unroll
    for (int m = 16; m; m >>= 1) {
      float so = __shfl_xor(b1, m, 64);
      int io = __shfl_xor(i1, m, 64);
      if (so < b1 || (so == b1 && io < i1)) { b1 = so; i1 = io; }
    }
    if (ct == 0) {
      int p = p0 + pt * 4 + ((i >> 2) << 6) + (i & 3);
      bv16[slice * NCAP + p] = b1;
      bi16[slice * NCAP + p] = i1;
    }
  }
}

// ---------------- merge 16 slices + scatter back ----------------
__global__ __launch_bounds__(256) void scatter_kernel(
    const float* __restrict__ bv16, const int* __restrict__ bi16,
    const int* __restrict__ flagcnt, const int* __restrict__ flaglist,
    int* __restrict__ idx, float* __restrict__ out_idx_f) {
  int n0 = *flagcnt;
  int n = n0 > NCAP ? NCAP : n0;
  int e = blockIdx.x * 256 + threadIdx.x;
  if (e >= n) return;
  float b1 = bv16[e];
  int i1 = bi16[e];
#pragma unroll
  for (int s = 1; s < 16; ++s) {
    float nb = bv16[s * NCAP + e];
    int ni = bi16[s * NCAP + e];
    if (nb < b1 || (nb == b1 && ni < i1)) { b1 = nb; i1 = ni; }
  }
  int p = flaglist[e];
  idx[p] = i1;
  out_idx_f[p] = (float)i1;
}

// ---------------- leftover cleanup (n > NCAP only; normally instant exit) ---
__global__ __launch_bounds__(256) void refine_left_kernel(
    const float* __restrict__ h, const float* __restrict__ cb,
    const float* __restrict__ h2f, const float* __restrict__ c2f,
    const int* __restrict__ flagcnt, const int* __restrict__ flaglist,
    int* __restrict__ idx, float* __restrict__ out_idx_f) {
  __shared__ float hrow[DIM];
  __shared__ float rb[256];
  __shared__ int ri[256];
  const int n = *flagcnt;
  for (int e = NCAP + blockIdx.x; e < n; e += gridDim.x) {
    const int p = flaglist[e];
    __syncthreads();
    if (threadIdx.x < DIM / 4)
      reinterpret_cast<float4*>(hrow)[threadIdx.x] =
          reinterpret_cast<const float4*>(h + (size_t)p * DIM)[threadIdx.x];
    __syncthreads();
    const float h2 = h2f[p];
    float b1 = 3.4e38f;
    int i1 = 0x7fffffff;
    for (int c = threadIdx.x; c < KCODES; c += 256) {
      const float4* crow = reinterpret_cast<const float4*>(cb + (size_t)c * DIM);
      float dot = 0.f;
#pragma unroll 16
      for (int d4 = 0; d4 < DIM / 4; ++d4) {
        float4 cv = crow[d4];
        dot = fmaf(hrow[4 * d4 + 0], cv.x, dot);
        dot = fmaf(hrow[4 * d4 + 1], cv.y, dot);
        dot = fmaf(hrow[4 * d4 + 2], cv.z, dot);
        dot = fmaf(hrow[4 * d4 + 3], cv.w, dot);
      }
      float A = h2 + c2f[c];
      float s = fmaf(-2.f, dot, A);
      if (s < b1) { b1 = s; i1 = c; }
    }
    rb[threadIdx.x] = b1;
    ri[threadIdx.x] = i1;
    __syncthreads();
    for (int step = 128; step; step >>= 1) {
      if (threadIdx.x < step) {
        float ob = rb[threadIdx.x + step];
        int oi = ri[threadIdx.x + step];
        if (ob < rb[threadIdx.x] || (ob == rb[threadIdx.x] && oi < ri[threadIdx.x])) {
          rb[threadIdx.x] = ob;
          ri[threadIdx.x] = oi;
        }
      }
      __syncthreads();
    }
    if (threadIdx.x == 0) { idx[p] = ri[0]; out_idx_f[p] = (float)ri[0]; }
  }
}

// ---------------- fallback: r7 fp32 argmin (8x8 tile) + 2-way merge ----------
__global__ __launch_bounds__(512, 2) void argmin_fp32_kernel(
    const float* __restrict__ h, const float* __restrict__ cb,
    const float* __restrict__ h2f, const float* __restrict__ c2f,
    float* __restrict__ bestval, int* __restrict__ bestidx) {
  __shared__ float hs[16][132];
  __shared__ float cs[16][260];
  const int t = threadIdx.x;
  const int ct = t & 31;
  const int pt = t >> 5;
  const int b = blockIdx.x;
  const int v = (b & 7) * 64 + (b >> 3);
  const int sblk = v >> 8;
  const int pblk = v & 255;
  const int p0 = pblk * 128;
  const int cbase = sblk * (KCODES / 2);
  float best[8]; int besti[8]; float h2r[8];
#pragma unroll
  for (int i = 0; i < 8; ++i) {
    best[i] = 3.4e38f; besti[i] = 0;
    h2r[i] = h2f[p0 + pt * 4 + ((i >> 2) << 6) + (i & 3)];
  }
#pragma unroll 1
  for (int cc = 0; cc < (KCODES / 2) / 256; ++cc) {
    const int c0 = cbase + cc * 256;
    float dot[8][8];
#pragma unroll
    for (int i = 0; i < 8; ++i)
#pragma unroll
      for (int j = 0; j < 8; ++j) dot[i][j] = 0.f;
#pragma unroll 1
    for (int dd = 0; dd < DIM / 16; ++dd) {
      const int d0 = dd * 16;
      {
        int p = t >> 2, k4 = (t & 3) << 2;
        float4 w = *reinterpret_cast<const float4*>(h + (p0 + p) * DIM + d0 + k4);
        hs[k4 + 0][p] = w.x; hs[k4 + 1][p] = w.y;
        hs[k4 + 2][p] = w.z; hs[k4 + 3][p] = w.w;
      }
#pragma unroll
      for (int l = 0; l < 2; ++l) {
        int F = t + l * 512;
        int c = F >> 2, k4 = (F & 3) << 2;
        float4 w = *reinterpret_cast<const float4*>(cb + (c0 + c) * DIM + d0 + k4);
        cs[k4 + 0][c] = w.x; cs[k4 + 1][c] = w.y;
        cs[k4 + 2][c] = w.z; cs[k4 + 3][c] = w.w;
      }
      __syncthreads();
#pragma unroll
      for (int k = 0; k < 16; ++k) {
        float hv[8], cv[8];
        *reinterpret_cast<float4*>(&hv[0]) = *reinterpret_cast<const float4*>(&hs[k][pt * 4]);
        *reinterpret_cast<float4*>(&hv[4]) = *reinterpret_cast<const float4*>(&hs[k][pt * 4 + 64]);
        *reinterpret_cast<float4*>(&cv[0]) = *reinterpret_cast<const float4*>(&cs[k][ct * 4]);
        *reinterpret_cast<float4*>(&cv[4]) = *reinterpret_cast<const float4*>(&cs[k][ct * 4 + 128]);
#pragma unroll
        for (int i = 0; i < 8; ++i)
#pragma unroll
          for (int j = 0; j < 8; ++j) dot[i][j] = fmaf(hv[i], cv[j], dot[i][j]);
      }
      __syncthreads();
    }
#pragma unroll
    for (int j = 0; j < 8; ++j) {
      int cl = c0 + (ct << 2) + ((j >> 2) << 7) + (j & 3);
      float cc2 = c2f[cl];
#pragma unroll
      for (int i = 0; i < 8; ++i) {
        float A = h2r[i] + cc2;
        float s = A - 2.0f * dot[i][j];
        if (s < best[i]) { best[i] = s; besti[i] = cl; }
      }
    }
  }
#pragma unroll
  for (int i = 0; i < 8; ++i) {
    float b1 = best[i]; int i1 = besti[i];
#pragma unroll
    for (int m = 16; m; m >>= 1) {
      float so = __shfl_xor(b1, m, 64);
      int io = __shfl_xor(i1, m, 64);
      if (so < b1 || (so == b1 && io < i1)) { b1 = so; i1 = io; }
    }
    if (ct == 0) {
      int p = p0 + pt * 4 + ((i >> 2) << 6) + (i & 3);
      bestval[sblk * NPTS + p] = b1;
      bestidx[sblk * NPTS + p] = i1;
    }
  }
}

__global__ __launch_bounds__(256) void merge2_kernel(
    const float* __restrict__ bestval, const int* __restrict__ bestidx,
    int* __restrict__ idx, float* __restrict__ out_idx_f) {
  int p = blockIdx.x * 256 + threadIdx.x;
  float v0 = bestval[p], v1 = bestval[NPTS + p];
  int i0 = bestidx[p], i1 = bestidx[NPTS + p];
  int w = (v1 < v0) ? i1 : i0;
  idx[p] = w;
  out_idx_f[p] = (float)w;
}

// ---------------- gather + finalize ----------------
__global__ __launch_bounds__(256) void gather_kernel(
    const float* __restrict__ h, const float* __restrict__ cb,
    const unsigned char* __restrict__ maskb, const int* __restrict__ idx,
    float* __restrict__ zq, float* __restrict__ partial) {
  int p = blockIdx.x * 4 + (threadIdx.x >> 6);
  int lane = threadIdx.x & 63;
  int ci = idx[p];
  float4 hv = reinterpret_cast<const float4*>(h)[p * (DIM / 4) + lane];
  float4 zv = reinterpret_cast<const float4*>(cb)[ci * (DIM / 4) + lane];
  float4 q;
  q.x = hv.x + (zv.x - hv.x);
  q.y = hv.y + (zv.y - hv.y);
  q.z = hv.z + (zv.z - hv.z);
  q.w = hv.w + (zv.w - hv.w);
  reinterpret_cast<float4*>(zq)[p * (DIM / 4) + lane] = q;
  float dx = hv.x - zv.x, dy = hv.y - zv.y, dz = hv.z - zv.z, dw = hv.w - zv.w;
  float s = (maskb[p] != 0) ? (dx * dx + dy * dy + dz * dz + dw * dw) : 0.f;
#pragma unroll
  for (int m = 32; m; m >>= 1) s += __shfl_xor(s, m, 64);
  __shared__ float bs[4];
  if (lane == 0) bs[threadIdx.x >> 6] = s;
  __syncthreads();
  if (threadIdx.x == 0) partial[blockIdx.x] = bs[0] + bs[1] + bs[2] + bs[3];
}

__global__ __launch_bounds__(256) void finalize_kernel(
    const float* __restrict__ partial, const unsigned char* __restrict__ maskb,
    float* __restrict__ out_losses) {
  __shared__ float red[256];
  __shared__ int redi[256];
  float s = 0.f;
  for (int i = threadIdx.x; i < NPTS / 4; i += 256) s += partial[i];
  int cnt = 0;
  for (int i = threadIdx.x; i < NPTS; i += 256) cnt += (maskb[i] != 0);
  red[threadIdx.x] = s;
  redi[threadIdx.x] = cnt;
  __syncthreads();
  for (int step = 128; step; step >>= 1) {
    if (threadIdx.x < step) {
      red[threadIdx.x] += red[threadIdx.x + step];
      redi[threadIdx.x] += redi[threadIdx.x + step];
    }
    __syncthreads();
  }
  if (threadIdx.x == 0) {
    float denom = (float)redi[0] * (float)DIM + 1e-8f;
    float loss = red[0] / denom;
    out_losses[0] = loss;
    out_losses[1] = loss;
  }
}

extern "C" void kernel_launch(void* const* d_in, const int* in_sizes, int n_in,
                              void* d_out, int out_size, void* d_ws, size_t ws_size,
                              hipStream_t stream) {
  const float* h = (const float*)d_in[0];
  const unsigned char* maskb = (const unsigned char*)d_in[1];
  const float* cb = (const float*)d_in[2];

  float* out = (float*)d_out;
  float* zq = out;
  float* out_idx_f = out + NPTS * DIM;
  float* out_losses = out + NPTS * DIM + NPTS;

  char* ws = (char*)d_ws;
  const size_t REQ = 42008576ULL;  // ~40 MB

  if (ws_size >= REQ) {
    float* h2f = (float*)(ws + 0);                    // 128K
    float* c2f = (float*)(ws + 131072);               // 32K
    float* bv = (float*)(ws + 163840);                // 512K
    int* bi = (int*)(ws + 688128);                    // 512K
    float* b2o = (float*)(ws + 1212416);              // 512K
    int* idx = (int*)(ws + 1736704);                  // 128K
    float* partial = (float*)(ws + 1867776);          // 32K
    int* flagcnt = (int*)(ws + 1900544);              // 4 (+pad)
    int* flaglist = (int*)(ws + 1904640);             // 128K
    unsigned short* hh = (unsigned short*)(ws + 2097152);    // 16M
    unsigned short* chh = (unsigned short*)(ws + 18874368);  // 4M
    float* hcomp = (float*)(ws + 23068672);           // 16M (NCAP x 1KB)
    float* h2comp = (float*)(ws + 39845888);          // 64K
    float* bv16 = (float*)(ws + 39911424);            // 1M
    int* bi16 = (int*)(ws + 40960000);                // 1M

    hipLaunchKernelGGL(bf16_norms_kernel, dim3(NPTS / 4), dim3(256), 0, stream,
                       h, hh, h2f, flagcnt);
    hipLaunchKernelGGL(bf16_norms_kernel, dim3(KCODES / 4), dim3(256), 0, stream,
                       cb, chh, c2f, (int*)nullptr);
    hipLaunchKernelGGL(mfma_argmin_kernel, dim3(512), dim3(512), 0, stream,
                       hh, chh, h2f, c2f, bv, bi, b2o);
    hipLaunchKernelGGL(merge_flag_kernel, dim3(NPTS / 256), dim3(256), 0, stream,
                       bv, bi, b2o, idx, out_idx_f, flagcnt, flaglist);
    hipLaunchKernelGGL(compact_kernel, dim3(2048), dim3(256), 0, stream,
                       h, h2f, flagcnt, flaglist, hcomp, h2comp);
    hipLaunchKernelGGL(refine_gemm_kernel, dim3((NCAP / 128) * 16), dim3(512), 0, stream,
                       hcomp, cb, h2comp, c2f, flagcnt, bv16, bi16);
    hipLaunchKernelGGL(scatter_kernel, dim3(NCAP / 256), dim3(256), 0, stream,
                       bv16, bi16, flagcnt, flaglist, idx, out_idx_f);
    hipLaunchKernelGGL(refine_left_kernel, dim3(2048), dim3(256), 0, stream,
                       h, cb, h2f, c2f, flagcnt, flaglist, idx, out_idx_f);
    hipLaunchKernelGGL(gather_kernel, dim3(NPTS / 4), dim3(256), 0, stream,
                       h, cb, maskb, idx, zq, partial);
    hipLaunchKernelGGL(finalize_kernel, dim3(1), dim3(256), 0, stream,
                       partial, maskb, out_losses);
  } else {
    float* h2f = (float*)(ws + 0);
    float* c2f = (float*)(ws + (128 << 10));
    float* bestval = (float*)(ws + (160 << 10));
    int* bestidx = (int*)(ws + (416 << 10));
    int* idx = (int*)(ws + (672 << 10));
    float* partial = (float*)(ws + (800 << 10));

    hipLaunchKernelGGL(norms_kernel, dim3(NPTS / 4), dim3(256), 0, stream, h, h2f);
    hipLaunchKernelGGL(norms_kernel, dim3(KCODES / 4), dim3(256), 0, stream, cb, c2f);
    hipLaunchKernelGGL(argmin_fp32_kernel, dim3(512), dim3(512), 0, stream,
                       h, cb, h2f, c2f, bestval, bestidx);
    hipLaunchKernelGGL(merge2_kernel, dim3(NPTS / 256), dim3(256), 0, stream,
                       bestval, bestidx, idx, out_idx_f);
    hipLaunchKernelGGL(gather_kernel, dim3(NPTS / 4), dim3(256), 0, stream,
                       h, cb, maskb, idx, zq, partial);
    hipLaunchKernelGGL(finalize_kernel, dim3(1), dim3(256), 0, stream,
                       partial, maskb, out_losses);
  }
}